// Round 2
// baseline (782.553 us; speedup 1.0000x reference)
//
#include <hip/hip_runtime.h>
#include <math.h>

// InnerPatchSoftShiftTriple: fused flash-style implementation (transposed k-order).
//
// s[l,k] = sum_{bb,aa} lat[:,R(l,bb,aa)] . knorm[:,R(k,bb,aa)]
// R(m,bb,aa) = Tinv(T(m)+bb-1) + (aa-1), valid iff T(m)+bb-1 in [0,L) and result in [0,L)
// T(m) = Tinv(m) = (m&63)*64 + (m>>6)   (H=W=64, involution)
//
// k processed as k = Tinv(k'), k' contiguous: band bb of column k needs base
// q = Tinv(k'+bb-1) and taps q-1,q,q+1 = three consecutive rows of knormT ->
// staged as tripled slots. Exact math incl. all flat-boundary zero-pads.

#define L   4096
#define RROWS 16
#define KSPLIT 8
#define KT  128
#define NT  4      // k'-tiles per ksplit: 512/128
#define GSTRIDE 196  // floats per g3 slot (3*64 + 4 pad): lane bank stride 4 -> conflict-free b128

// ---- ws layout (bytes) ----
#define OFF_LATT   0u          // float[2][4096][64]  latterT (raw)
#define OFF_FORMT  2097152u    // float[2][4096][64]  formerT
#define OFF_INVN   4194304u    // float[2][4096]
#define OFF_TAP    4227072u    // int[4096][9]
#define OFF_FLAG   4374528u    // int[4096]
#define OFF_ROWS   4390912u    // int[4096]
#define OFF_CNT    4407296u    // int[1]
#define OFF_PART   4407552u    // float[2][256][8][16][68]  (m, s, pad2, acc[64])

// ---------------- prep: copy passthrough channels, zero shift, tap table, zero cnt ----------
__global__ void k_prep(const float4* __restrict__ x4, float4* __restrict__ out4,
                       int* __restrict__ tapidx, int* __restrict__ cnt)
{
    int i = blockIdx.x * 256 + threadIdx.x;
    if (i < 262144) {                       // copy former+latter (2 x 128 x 4096 f32 as f4)
        int b = i >> 17, j = i & 131071;
        out4[b * 196608 + j] = x4[b * 131072 + j];
    } else if (i < 393216) {                // zero shift region (2 x 64 x 4096)
        int z = i - 262144; int b = z >> 16, j = z & 65535;
        out4[b * 196608 + 131072 + j] = make_float4(0.f, 0.f, 0.f, 0.f);
    } else if (i < 397312) {                // tap table (CORRECT order: b inner, a outer)
        int l = i - 393216;
        int tl0 = ((l & 63) << 6) + (l >> 6);   // T(l)
        #pragma unroll
        for (int bb = 0; bb < 3; ++bb)
            #pragma unroll
            for (int aa = 0; aa < 3; ++aa) {
                int tl = tl0 + bb - 1;
                int r = -1;
                if (tl >= 0 && tl < L) {
                    int p = ((tl & 63) << 6) + (tl >> 6) + (aa - 1);  // Tinv(tl) + a'
                    if (p >= 0 && p < L) r = p;
                }
                tapidx[l * 9 + bb * 3 + aa] = r;
            }
    } else if (i == 397312) {
        cnt[0] = 0;
    }
}

// ---------------- transpose + norms ----------------
__global__ void k_norm(const float* __restrict__ x, float* __restrict__ latT,
                       float* __restrict__ formerT, float* __restrict__ invn)
{
    int tid = blockIdx.x * 256 + threadIdx.x;   // 8192 threads
    int b = tid >> 12, l = tid & 4095;
    const float* xb = x + (size_t)b * 128 * 4096;
    float4 row[16];
    float ss = 0.f;
    #pragma unroll
    for (int c4 = 0; c4 < 16; ++c4) {
        float4 v;
        v.x = xb[(64 + c4 * 4 + 0) * 4096 + l];
        v.y = xb[(64 + c4 * 4 + 1) * 4096 + l];
        v.z = xb[(64 + c4 * 4 + 2) * 4096 + l];
        v.w = xb[(64 + c4 * 4 + 3) * 4096 + l];
        row[c4] = v;
        ss += v.x * v.x + v.y * v.y + v.z * v.z + v.w * v.w;
    }
    float inv = 1.f / fmaxf(sqrtf(ss), 1e-4f);
    invn[b * 4096 + l] = inv;
    float* lrow = latT + ((size_t)(b * 4096 + l)) * 64;
    #pragma unroll
    for (int c4 = 0; c4 < 16; ++c4) *(float4*)(lrow + c4 * 4) = row[c4];
    float* frow = formerT + ((size_t)(b * 4096 + l)) * 64;
    #pragma unroll
    for (int c4 = 0; c4 < 16; ++c4) {
        float4 v;
        v.x = xb[(c4 * 4 + 0) * 4096 + l];
        v.y = xb[(c4 * 4 + 1) * 4096 + l];
        v.z = xb[(c4 * 4 + 2) * 4096 + l];
        v.w = xb[(c4 * 4 + 3) * 4096 + l];
        *(float4*)(frow + c4 * 4) = v;
    }
}

// ---------------- flags + compaction ----------------
__global__ void k_compact(const float* __restrict__ mask, int* __restrict__ flagA,
                          int* __restrict__ rows, int* __restrict__ cnt)
{
    int l = blockIdx.x * 256 + threadIdx.x;
    if (l >= L) return;
    int f = (mask[l] > 0.5f) ? 1 : 0;
    flagA[l] = f;
    if (f) { int p = atomicAdd(cnt, 1); rows[p] = l; }
}

// ---------------- main flash kernel (transposed k-order, tripled column staging) ----------------
__global__ __launch_bounds__(256, 1)
void k_flash(const float* __restrict__ latT, const float* __restrict__ formerT,
             const float* __restrict__ invn, const int* __restrict__ tapidx,
             const int* __restrict__ flagA, const int* __restrict__ rows,
             const int* __restrict__ cnt, float* __restrict__ part)
{
    const int t = threadIdx.x;
    const int rt = blockIdx.x, ks = blockIdx.y, b = blockIdx.z;
    const int count = cnt[0];
    const int base = rt * RROWS;
    if (base >= count) return;
    const int nact = min(RROWS, count - base);

    __shared__ __align__(16) float u_s[RROWS * 9 * 64];        // 36864 B
    __shared__ __align__(16) float g3_s[(KT + 2) * GSTRIDE];   // 101920 B (also former[128][68])
    __shared__ __align__(16) float st_s[RROWS * 132];          // 8448 B
    __shared__ int rl_s[RROWS];

    if (t < RROWS) rl_s[t] = rows[base + min(t, nact - 1)];
    __syncthreads();

    const float* latTb    = latT    + (size_t)b * L * 64;
    const float* formerTb = formerT + (size_t)b * L * 64;
    const float* invnb    = invn    + b * L;

    // U gather: u[r][tap][c] = latT[tapidx[rl][tap]][c] (0 if invalid). 2304 float4 items.
    #pragma unroll
    for (int j = 0; j < 9; ++j) {
        int id = t + 256 * j;                 // exactly covers 2304
        int r = id / 144;
        int rem = id - r * 144;
        int tap = rem >> 4, c4 = rem & 15;
        int ridx = tapidx[rl_s[r] * 9 + tap];
        float4 val = make_float4(0.f, 0.f, 0.f, 0.f);
        if (ridx >= 0) val = *(const float4*)(latTb + ridx * 64 + c4 * 4);
        *(float4*)(u_s + (r * 9 + tap) * 64 + c4 * 4) = val;
    }
    // u_s first read happens after the staging __syncthreads below.

    const int rme = t >> 4, cg = t & 15;   // softmax/PV mapping
    const int wv = t >> 6, lane = t & 63;  // score mapping: 4 rows per wave, 2 k' per lane
    const int r0 = wv * 4;
    float m_run = -INFINITY, s_run = 0.f;
    float4 acc = make_float4(0.f, 0.f, 0.f, 0.f);

    const int kp_base = ks * (KT * NT);    // base k' (transposed flat) for this split

    for (int kt = 0; kt < NT; ++kt) {
        const int k0p = kp_base + kt * KT;
        __syncthreads();   // prev tile's PV done with g3 region (also covers u_s/rl_s writes)

        // stage g3: slot s in [0,130), m' = k0p-1+s; g3[s][aa][c] = knorm[:, Tinv(m')+aa-1]
        #pragma unroll
        for (int j = 0; j < 25; ++j) {
            int id = t + 256 * j;             // 6240 items
            if (id < (KT + 2) * 48) {
                int s = id / 48;
                int rem = id - s * 48;
                int aa = rem >> 4, c4 = rem & 15;
                int mp = k0p - 1 + s;
                float4 val = make_float4(0.f, 0.f, 0.f, 0.f);
                if (mp >= 0 && mp < L) {
                    int p = ((mp & 63) << 6) + (mp >> 6) + (aa - 1);   // Tinv(m') + a'
                    if (p >= 0 && p < L) {
                        val = *(const float4*)(latTb + p * 64 + c4 * 4);
                        float iv = invnb[p];
                        val.x *= iv; val.y *= iv; val.z *= iv; val.w *= iv;
                    }
                }
                *(float4*)(g3_s + s * GSTRIDE + aa * 64 + c4 * 4) = val;
            }
        }
        __syncthreads();

        // scores: s[r0+i][j] = sum_{tap,c} u[r0+i][tap][c] * g3[j+bb][aa][c]
        float s8[8];
        #pragma unroll
        for (int i = 0; i < 8; ++i) s8[i] = 0.f;
        for (int tap = 0; tap < 9; ++tap) {
            const int bb = tap / 3, aa = tap - 3 * (tap / 3);
            const float* g0p = g3_s + (lane + bb) * GSTRIDE + aa * 64;
            const float* g1p = g3_s + (lane + 64 + bb) * GSTRIDE + aa * 64;
            const float* up  = u_s + (r0 * 9 + tap) * 64;
            #pragma unroll
            for (int c4 = 0; c4 < 16; ++c4) {
                float4 g0 = *(const float4*)(g0p + c4 * 4);
                float4 g1 = *(const float4*)(g1p + c4 * 4);
                #pragma unroll
                for (int i = 0; i < 4; ++i) {
                    float4 uu = *(const float4*)(up + i * 9 * 64 + c4 * 4);
                    s8[i * 2 + 0] += uu.x * g0.x + uu.y * g0.y + uu.z * g0.z + uu.w * g0.w;
                    s8[i * 2 + 1] += uu.x * g1.x + uu.y * g1.y + uu.z * g1.z + uu.w * g1.w;
                }
            }
        }
        #pragma unroll
        for (int i = 0; i < 4; ++i) {
            st_s[(r0 + i) * 132 + lane]      = s8[i * 2 + 0];
            st_s[(r0 + i) * 132 + lane + 64] = s8[i * 2 + 1];
        }
        __syncthreads();

        // mask + online softmax (16 lanes per row); column j -> korig = Tinv(k0p+j)
        float tmax = -INFINITY;
        float sv[8];
        #pragma unroll
        for (int jj = 0; jj < 8; ++jj) {
            int j = cg + 16 * jj;
            float s = st_s[rme * 132 + j];
            int kp = k0p + j;
            int korig = ((kp & 63) << 6) + (kp >> 6);
            if (flagA[korig] != 0) s = -INFINITY;
            sv[jj] = s;
            tmax = fmaxf(tmax, s);
        }
        #pragma unroll
        for (int o = 1; o < 16; o <<= 1) tmax = fmaxf(tmax, __shfl_xor(tmax, o, 64));
        float newm = fmaxf(m_run, tmax);
        if (newm > -INFINITY) {
            float fac = __expf(m_run - newm);    // m_run=-inf -> 0
            s_run *= fac;
            acc.x *= fac; acc.y *= fac; acc.z *= fac; acc.w *= fac;
            float tsum = 0.f;
            #pragma unroll
            for (int jj = 0; jj < 8; ++jj) {
                int j = cg + 16 * jj;
                float p = __expf(sv[jj] - newm);  // sv=-inf -> 0
                st_s[rme * 132 + j] = p;
                tsum += p;
            }
            #pragma unroll
            for (int o = 1; o < 16; o <<= 1) tsum += __shfl_xor(tsum, o, 64);
            s_run += tsum;
            m_run = newm;
        } else {
            #pragma unroll
            for (int jj = 0; jj < 8; ++jj) st_s[rme * 132 + cg + 16 * jj] = 0.f;
        }
        // stage former tile into g3 region (stride 68): slot j = formerT[Tinv(k0p+j)]
        // (safe: all score-phase reads of g3_s completed before the sync above)
        #pragma unroll
        for (int j = 0; j < 8; ++j) {
            int id = t + 256 * j;                 // exactly 2048
            int kcol = id >> 4, c4 = id & 15;
            int kp = k0p + kcol;
            int korig = ((kp & 63) << 6) + (kp >> 6);
            float4 val = *(const float4*)(formerTb + (size_t)korig * 64 + c4 * 4);
            *(float4*)(g3_s + kcol * 68 + c4 * 4) = val;
        }
        __syncthreads();

        // PV: acc[c] += p[rme][j] * former[c][korig(j)]
        #pragma unroll 4
        for (int k = 0; k < KT; ++k) {
            float p = st_s[rme * 132 + k];
            float4 f = *(const float4*)(g3_s + k * 68 + cg * 4);
            acc.x += p * f.x; acc.y += p * f.y; acc.z += p * f.z; acc.w += p * f.w;
        }
    }
    // partials
    float* pp = part + ((size_t)((b * 256 + rt) * KSPLIT + ks) * RROWS + rme) * 68;
    if (cg == 0) { pp[0] = m_run; pp[1] = s_run; }
    *(float4*)(pp + 4 + cg * 4) = acc;
}

// ---------------- combine k-split partials, write shift ----------------
__global__ void k_reduce(const int* __restrict__ rows, const int* __restrict__ cnt,
                         const float* __restrict__ part, float* __restrict__ out)
{
    int t = threadIdx.x;
    int rme = t >> 4, cg = t & 15;
    int rt = blockIdx.x, b = blockIdx.y;
    int count = cnt[0];
    int slot = rt * 16 + rme;
    if (slot >= count) return;
    int l = rows[slot];
    const float* pb = part + ((size_t)((b * 256 + rt) * KSPLIT) * RROWS + rme) * 68;
    const int kstride = RROWS * 68;
    float M = -INFINITY;
    float ms[KSPLIT];
    #pragma unroll
    for (int i = 0; i < KSPLIT; ++i) { ms[i] = pb[i * kstride + 0]; M = fmaxf(M, ms[i]); }
    if (!(M > -INFINITY)) return;            // all masked: leave zeros
    float S = 0.f;
    float ww[KSPLIT];
    #pragma unroll
    for (int i = 0; i < KSPLIT; ++i) { float w = __expf(ms[i] - M); ww[i] = w; S += pb[i * kstride + 1] * w; }
    float4 pv = make_float4(0.f, 0.f, 0.f, 0.f);
    #pragma unroll
    for (int i = 0; i < KSPLIT; ++i) {
        const float4 a = *(const float4*)(pb + i * kstride + 4 + cg * 4);
        pv.x += ww[i] * a.x; pv.y += ww[i] * a.y; pv.z += ww[i] * a.z; pv.w += ww[i] * a.w;
    }
    float inv = (S > 0.f) ? 1.f / S : 0.f;
    float* ob = out + (size_t)b * 786432 + 128 * 4096 + l;
    ob[(cg * 4 + 0) * 4096] = pv.x * inv;
    ob[(cg * 4 + 1) * 4096] = pv.y * inv;
    ob[(cg * 4 + 2) * 4096] = pv.z * inv;
    ob[(cg * 4 + 3) * 4096] = pv.w * inv;
}

extern "C" void kernel_launch(void* const* d_in, const int* in_sizes, int n_in,
                              void* d_out, int out_size, void* d_ws, size_t ws_size,
                              hipStream_t stream)
{
    const float* x    = (const float*)d_in[0];
    const float* mask = (const float*)d_in[1];
    float* out = (float*)d_out;
    char* ws = (char*)d_ws;

    float* latT    = (float*)(ws + OFF_LATT);
    float* formerT = (float*)(ws + OFF_FORMT);
    float* invn    = (float*)(ws + OFF_INVN);
    int*   tapidx  = (int*)  (ws + OFF_TAP);
    int*   flagA   = (int*)  (ws + OFF_FLAG);
    int*   rows    = (int*)  (ws + OFF_ROWS);
    int*   cnt     = (int*)  (ws + OFF_CNT);
    float* part    = (float*)(ws + OFF_PART);

    k_prep<<<1553, 256, 0, stream>>>((const float4*)x, (float4*)out, tapidx, cnt);
    k_norm<<<32, 256, 0, stream>>>(x, latT, formerT, invn);
    k_compact<<<16, 256, 0, stream>>>(mask, flagA, rows, cnt);
    k_flash<<<dim3(256, KSPLIT, 2), 256, 0, stream>>>(latT, formerT, invn, tapidx, flagA, rows, cnt, part);
    k_reduce<<<dim3(256, 2), 256, 0, stream>>>(rows, cnt, part, out);
}

// Round 3
// 166.074 us; speedup vs baseline: 4.7121x; 4.7121x over previous
//
#include <hip/hip_runtime.h>
#include <math.h>

// InnerPatchSoftShiftTriple — MFMA bf16 flash implementation (transposed k-order).
// s[l,k] = sum_{bb,aa,c} lat[c][R(l,bb,aa)] * knorm[c][R(k,bb,aa)]
// R(m,bb,aa) = Tinv(T(m)+bb-1) + (aa-1), valid iff intermediate/final in [0,L)
// T(m)=Tinv(m)=((m&63)<<6)|(m>>6).  k swept as k=Tinv(k'), k' contiguous.
// Score GEMM: S^T = G·U^T (M=k'cols, N=rows, K=576) via mfma_f32_16x16x32_bf16.
// PV GEMM: out = P·F (M=rows32, K=32 cols/wave, N=64 ch).

#define L 4096

typedef unsigned int   u32;
typedef unsigned short u16;
typedef short  short8 __attribute__((ext_vector_type(8)));
typedef float  f32x4  __attribute__((ext_vector_type(4)));

#define MFMA(a, b, c) __builtin_amdgcn_mfma_f32_16x16x32_bf16((a), (b), (c), 0, 0, 0)

__device__ __forceinline__ u16 f2bf(float f) {
    u32 u = __float_as_uint(f);
    u32 r = (u + 0x7FFFu + ((u >> 16) & 1u)) >> 16;
    return (u16)r;
}

// ---- ws layout (bytes) ----
#define OFF_LATB  0u          // u16[2][4096][64] raw latter (transposed)
#define OFF_KNB   1048576u    // u16[2][4096][64] normalized latter
#define OFF_FORB  2097152u    // u16[2][4096][64] former
#define OFF_FBITS 3145728u    // u32[128] flag bitmap in transposed order
#define OFF_ROWS  3146240u    // int[4096]
#define OFF_CNT   3162624u    // int
#define OFF_PART  3211264u    // [2][128][8] segs x (32 rows x 144B: m f32, s f32, pad, 64 bf16)
// part end = 3211264 + 2*128*8*4608 = 12,648,448 B (< 13.8MB known-good footprint)

// ---------------- prep: copy passthrough, zero shift, zero fbits/cnt ----------------
__global__ void k_prep(const float4* __restrict__ x4, float4* __restrict__ out4,
                       u32* __restrict__ fbits, int* __restrict__ cnt)
{
    int i = blockIdx.x * 256 + threadIdx.x;
    if (i < 262144) {
        int b = i >> 17, j = i & 131071;
        out4[b * 196608 + j] = x4[b * 131072 + j];
    } else if (i < 393216) {
        int z = i - 262144; int b = z >> 16, j = z & 65535;
        out4[b * 196608 + 131072 + j] = make_float4(0.f, 0.f, 0.f, 0.f);
    } else if (i < 393344) {
        fbits[i - 393216] = 0u;
    } else if (i == 393344) {
        cnt[0] = 0;
    }
}

// ---------------- transpose + normalize + bf16 pack ----------------
__global__ void k_norm(const float* __restrict__ x, u16* __restrict__ latb,
                       u16* __restrict__ knb, u16* __restrict__ forb)
{
    int tid = blockIdx.x * 256 + threadIdx.x;   // 8192
    int b = tid >> 12, l = tid & 4095;
    const float* xb = x + (size_t)b * 524288;
    float v[64]; float ss = 0.f;
    #pragma unroll
    for (int c = 0; c < 64; ++c) { v[c] = xb[(64 + c) * 4096 + l]; ss += v[c] * v[c]; }
    float inv = 1.f / fmaxf(sqrtf(ss), 1e-4f);
    u16* lr = latb + (size_t)(b * 4096 + l) * 64;
    u16* kr = knb  + (size_t)(b * 4096 + l) * 64;
    #pragma unroll
    for (int c8 = 0; c8 < 8; ++c8) {
        uint4 pl, pk;
        u32 wl[4], wk[4];
        #pragma unroll
        for (int i = 0; i < 4; ++i) {
            float a = v[c8 * 8 + 2 * i], bb2 = v[c8 * 8 + 2 * i + 1];
            wl[i] = (u32)f2bf(a) | ((u32)f2bf(bb2) << 16);
            wk[i] = (u32)f2bf(a * inv) | ((u32)f2bf(bb2 * inv) << 16);
        }
        pl.x = wl[0]; pl.y = wl[1]; pl.z = wl[2]; pl.w = wl[3];
        pk.x = wk[0]; pk.y = wk[1]; pk.z = wk[2]; pk.w = wk[3];
        *(uint4*)(lr + c8 * 8) = pl;
        *(uint4*)(kr + c8 * 8) = pk;
    }
    u16* fr = forb + (size_t)(b * 4096 + l) * 64;
    #pragma unroll
    for (int c8 = 0; c8 < 8; ++c8) {
        u32 wf[4];
        #pragma unroll
        for (int i = 0; i < 4; ++i) {
            float a = xb[(c8 * 8 + 2 * i) * 4096 + l];
            float bb2 = xb[(c8 * 8 + 2 * i + 1) * 4096 + l];
            wf[i] = (u32)f2bf(a) | ((u32)f2bf(bb2) << 16);
        }
        uint4 pf; pf.x = wf[0]; pf.y = wf[1]; pf.z = wf[2]; pf.w = wf[3];
        *(uint4*)(fr + c8 * 8) = pf;
    }
}

// ---------------- flags: compaction + transposed bitmap ----------------
__global__ void k_compact(const float* __restrict__ mask, int* __restrict__ rows,
                          int* __restrict__ cnt, u32* __restrict__ fbits)
{
    int l = blockIdx.x * 256 + threadIdx.x;
    if (l >= L) return;
    if (mask[l] > 0.5f) {
        int p = atomicAdd(cnt, 1); rows[p] = l;
        int kp = ((l & 63) << 6) | (l >> 6);
        atomicOr(&fbits[kp >> 5], 1u << (kp & 31));
    }
}

// ---------------- main flash kernel (MFMA) ----------------
// LDS map (bytes):
//  G_OFF 0      : g_s u16[128][72]  (18,432)  | aliased by F_s u16[64][136] (17,408)
//  U_OFF 18432  : u_s u16[32][584]  (37,376)  | aliased by um f32[128][66] (33,792)
//  P_OFF 55808  : p_s u16[4][32][40] (10,240)
//  FAC   66048  : fac_s f32[4][32]  (512)
//  RL    66560  : rl_s int[32]      (128)     total 66,688 -> 2 blocks/CU
__global__ __launch_bounds__(256, 2)
void k_flash(const u16* __restrict__ latb, const u16* __restrict__ knb,
             const u16* __restrict__ forb, const u32* __restrict__ fbits,
             const int* __restrict__ rows, const int* __restrict__ cnt,
             char* __restrict__ part)
{
    __shared__ __align__(16) char smem[66688];
    const int t = threadIdx.x;
    const int rt = blockIdx.x, ks = blockIdx.y, b = blockIdx.z;
    const int count = cnt[0];
    const int base = rt * 32;
    if (base >= count) return;
    const int nact = min(32, count - base);

    u16*   g_s   = (u16*)(smem);
    u16*   u_s   = (u16*)(smem + 18432);
    u16*   p_s   = (u16*)(smem + 55808);
    float* fac_s = (float*)(smem + 66048);
    int*   rl_s  = (int*)(smem + 66560);

    if (t < 32) rl_s[t] = rows[base + min(t, nact - 1)];
    __syncthreads();

    const size_t boff = (size_t)b * 4096 * 64;

    // stage U: u_s[r][tap*64+c] = latb[R(l,tap)][c]  (2304 x 16B)
    #pragma unroll
    for (int j = 0; j < 9; ++j) {
        int id = t + 256 * j;
        int r = id / 72, rem = id - r * 72;
        int tap = rem >> 3, c8 = rem & 7;
        int bb = tap / 3, aa = tap - 3 * bb;
        int l = rl_s[r];
        int tl = ((l & 63) << 6) | (l >> 6);
        int mp = tl + bb - 1;
        uint4 val = make_uint4(0, 0, 0, 0);
        if (mp >= 0 && mp < L) {
            int q = (((mp & 63) << 6) | (mp >> 6)) + aa - 1;
            if (q >= 0 && q < L)
                val = *(const uint4*)(latb + boff + (size_t)q * 64 + c8 * 8);
        }
        *(uint4*)(u_s + r * 584 + tap * 64 + c8 * 8) = val;
    }

    const int ln = t & 15, g = (t >> 4) & 3, w = t >> 6;
    float mrun[2] = {-INFINITY, -INFINITY}, srun[2] = {0.f, 0.f};
    f32x4 acc[2][4];
    #pragma unroll
    for (int i = 0; i < 2; ++i)
        #pragma unroll
        for (int jx = 0; jx < 4; ++jx) acc[i][jx] = (f32x4){0.f, 0.f, 0.f, 0.f};

    const int kp0 = ks * 512;
    for (int kt = 0; kt < 4; ++kt) {
        const int k0p = kp0 + kt * 128;
        f32x4 sc[2][2];
        #pragma unroll
        for (int i = 0; i < 2; ++i)
            #pragma unroll
            for (int jx = 0; jx < 2; ++jx) sc[i][jx] = (f32x4){0.f, 0.f, 0.f, 0.f};

        for (int tap = 0; tap < 9; ++tap) {
            const int bb = tap / 3, aa = tap - 3 * (tap / 3);
            __syncthreads();   // g/F region free (prev consumers done)
            // stage g_tap: g_s[col][c] = knorm[Rcol(k0p+col,tap)][c]  (1024 x 16B)
            #pragma unroll
            for (int j = 0; j < 4; ++j) {
                int id = t + 256 * j;
                int col = id >> 3, c8 = id & 7;
                int mp = k0p + col + bb - 1;
                uint4 val = make_uint4(0, 0, 0, 0);
                if (mp >= 0 && mp < L) {
                    int q = (((mp & 63) << 6) | (mp >> 6)) + aa - 1;
                    if (q >= 0 && q < L)
                        val = *(const uint4*)(knb + boff + (size_t)q * 64 + c8 * 8);
                }
                *(uint4*)(g_s + col * 72 + c8 * 8) = val;
            }
            __syncthreads();
            #pragma unroll
            for (int Ksi = 0; Ksi < 2; ++Ksi) {
                short8 bu0 = *(const short8*)(u_s + ln * 584        + tap * 64 + Ksi * 32 + g * 8);
                short8 bu1 = *(const short8*)(u_s + (16 + ln) * 584 + tap * 64 + Ksi * 32 + g * 8);
                short8 ag0 = *(const short8*)(g_s + (w * 32 + ln) * 72      + Ksi * 32 + g * 8);
                short8 ag1 = *(const short8*)(g_s + (w * 32 + 16 + ln) * 72 + Ksi * 32 + g * 8);
                sc[0][0] = MFMA(ag0, bu0, sc[0][0]);
                sc[0][1] = MFMA(ag0, bu1, sc[0][1]);
                sc[1][0] = MFMA(ag1, bu0, sc[1][0]);
                sc[1][1] = MFMA(ag1, bu1, sc[1][1]);
            }
        }
        __syncthreads();   // all score reads done before F overwrites g region

        // ---- mask + online softmax (S^T frag: lane holds l=Tn*16+ln, k=Mt*16+g*4+j)
        u32 bits = fbits[(k0p >> 5) + w];
        #pragma unroll
        for (int Tn = 0; Tn < 2; ++Tn) {
            float sv[2][4]; float mx = -INFINITY;
            #pragma unroll
            for (int Mt = 0; Mt < 2; ++Mt)
                #pragma unroll
                for (int jj = 0; jj < 4; ++jj) {
                    float s = sc[Mt][Tn][jj];
                    if ((bits >> (Mt * 16 + g * 4 + jj)) & 1) s = -INFINITY;
                    sv[Mt][jj] = s; mx = fmaxf(mx, s);
                }
            mx = fmaxf(mx, __shfl_xor(mx, 16));
            mx = fmaxf(mx, __shfl_xor(mx, 32));
            float newm = fmaxf(mrun[Tn], mx);
            float fac, tsum = 0.f;
            u16 pbv[2][4];
            if (newm > -INFINITY) {
                fac = __expf(mrun[Tn] - newm);
                #pragma unroll
                for (int Mt = 0; Mt < 2; ++Mt)
                    #pragma unroll
                    for (int jj = 0; jj < 4; ++jj) {
                        float p = __expf(sv[Mt][jj] - newm);
                        tsum += p; pbv[Mt][jj] = f2bf(p);
                    }
            } else {
                fac = 1.f;
                #pragma unroll
                for (int Mt = 0; Mt < 2; ++Mt)
                    #pragma unroll
                    for (int jj = 0; jj < 4; ++jj) pbv[Mt][jj] = 0;
            }
            tsum += __shfl_xor(tsum, 16);
            tsum += __shfl_xor(tsum, 32);
            srun[Tn] = srun[Tn] * fac + tsum;
            mrun[Tn] = newm;
            #pragma unroll
            for (int Mt = 0; Mt < 2; ++Mt) {
                uint2 pw;
                pw.x = (u32)pbv[Mt][0] | ((u32)pbv[Mt][1] << 16);
                pw.y = (u32)pbv[Mt][2] | ((u32)pbv[Mt][3] << 16);
                *(uint2*)(p_s + w * 1280 + (Tn * 16 + ln) * 40 + Mt * 16 + g * 4) = pw;
            }
            if (g == 0) fac_s[w * 32 + Tn * 16 + ln] = fac;
        }

        // ---- stage F into g region: F_s[ch][col] (transposed former tile)
        {
            u16* F_s = g_s;
            int cp = t & 63, chq = t >> 6;
            int kpA = k0p + 2 * cp, kpB = kpA + 1;
            int kA = ((kpA & 63) << 6) | (kpA >> 6);
            int kB = ((kpB & 63) << 6) | (kpB >> 6);
            const u32* pa = (const u32*)(forb + boff + (size_t)kA * 64 + chq * 16);
            const u32* pc = (const u32*)(forb + boff + (size_t)kB * 64 + chq * 16);
            uint4 A0 = *(const uint4*)pa, A1 = *(const uint4*)(pa + 4);
            uint4 B0 = *(const uint4*)pc, B1 = *(const uint4*)(pc + 4);
            u32 av[8] = {A0.x, A0.y, A0.z, A0.w, A1.x, A1.y, A1.z, A1.w};
            u32 bv[8] = {B0.x, B0.y, B0.z, B0.w, B1.x, B1.y, B1.z, B1.w};
            #pragma unroll
            for (int i = 0; i < 8; ++i) {
                u32 w0 = (av[i] & 0xffffu) | (bv[i] << 16);
                u32 w1 = (av[i] >> 16) | (bv[i] & 0xffff0000u);
                *(u32*)((char*)F_s + (chq * 16 + 2 * i) * 272 + cp * 4) = w0;
                *(u32*)((char*)F_s + (chq * 16 + 2 * i + 1) * 272 + cp * 4) = w1;
            }
        }
        __syncthreads();

        // ---- rescale acc, then PV MFMA
        #pragma unroll
        for (int Ml = 0; Ml < 2; ++Ml) {
            f32x4 fr = *(f32x4*)(fac_s + w * 32 + Ml * 16 + g * 4);
            #pragma unroll
            for (int ct = 0; ct < 4; ++ct)
                #pragma unroll
                for (int jj = 0; jj < 4; ++jj)
                    acc[Ml][ct][jj] *= fr[jj];
        }
        short8 pa0 = *(const short8*)(p_s + w * 1280 + ln * 40 + g * 8);
        short8 pa1 = *(const short8*)(p_s + w * 1280 + (16 + ln) * 40 + g * 8);
        #pragma unroll
        for (int ct = 0; ct < 4; ++ct) {
            short8 fb = *(const short8*)(g_s + (ct * 16 + ln) * 136 + w * 32 + g * 8);
            acc[0][ct] = MFMA(pa0, fb, acc[0][ct]);
            acc[1][ct] = MFMA(pa1, fb, acc[1][ct]);
        }
    }

    // ---- merge 4 waves in LDS (um aliases u_s region), write bf16 partials
    __syncthreads();
    float* um = (float*)u_s;   // [128][66]
    if (g == 0) {
        #pragma unroll
        for (int Tn = 0; Tn < 2; ++Tn) {
            um[(w * 32 + Tn * 16 + ln) * 66 + 0] = mrun[Tn];
            um[(w * 32 + Tn * 16 + ln) * 66 + 1] = srun[Tn];
        }
    }
    #pragma unroll
    for (int Ml = 0; Ml < 2; ++Ml)
        #pragma unroll
        for (int ct = 0; ct < 4; ++ct)
            #pragma unroll
            for (int jj = 0; jj < 4; ++jj)
                um[(w * 32 + Ml * 16 + g * 4 + jj) * 66 + 2 + ct * 16 + ln] = acc[Ml][ct][jj];
    __syncthreads();
    {
        int row = t >> 3, cq = t & 7;
        float m4[4], s4[4];
        #pragma unroll
        for (int wv = 0; wv < 4; ++wv) {
            m4[wv] = um[(wv * 32 + row) * 66];
            s4[wv] = um[(wv * 32 + row) * 66 + 1];
        }
        float M = fmaxf(fmaxf(m4[0], m4[1]), fmaxf(m4[2], m4[3]));
        float S = 0.f; float wx[4];
        if (M > -INFINITY) {
            #pragma unroll
            for (int wv = 0; wv < 4; ++wv) { wx[wv] = __expf(m4[wv] - M); S += s4[wv] * wx[wv]; }
        } else {
            wx[0] = wx[1] = wx[2] = wx[3] = 0.f;
        }
        char* pp = part + ((size_t)((b * 128 + rt) * 8 + ks)) * 4608 + row * 144;
        u16 h[8];
        #pragma unroll
        for (int i = 0; i < 8; ++i) {
            int ch = cq * 8 + i;
            float v = 0.f;
            #pragma unroll
            for (int wv = 0; wv < 4; ++wv) v += wx[wv] * um[(wv * 32 + row) * 66 + 2 + ch];
            h[i] = f2bf(v);
        }
        if (cq == 0) { *(float*)pp = M; *(float*)(pp + 4) = S; }
        uint4 hw;
        hw.x = (u32)h[0] | ((u32)h[1] << 16); hw.y = (u32)h[2] | ((u32)h[3] << 16);
        hw.z = (u32)h[4] | ((u32)h[5] << 16); hw.w = (u32)h[6] | ((u32)h[7] << 16);
        *(uint4*)(pp + 16 + cq * 16) = hw;
    }
}

// ---------------- combine k-split partials, write shift ----------------
__global__ void k_reduce(const int* __restrict__ rows, const int* __restrict__ cnt,
                         const char* __restrict__ part, float* __restrict__ out)
{
    int t = threadIdx.x;
    int row = t >> 3, cq = t & 7;
    int rt = blockIdx.x, b = blockIdx.y;
    int count = cnt[0];
    int slot = rt * 32 + row;
    if (slot >= count) return;
    int l = rows[slot];
    const char* pb = part + ((size_t)((b * 128 + rt) * 8)) * 4608 + row * 144;
    float M = -INFINITY, m8[8], s8[8];
    #pragma unroll
    for (int k = 0; k < 8; ++k) {
        m8[k] = *(const float*)(pb + k * 4608);
        s8[k] = *(const float*)(pb + k * 4608 + 4);
        M = fmaxf(M, m8[k]);
    }
    if (!(M > -INFINITY)) return;
    float S = 0.f; float accv[8] = {0.f, 0.f, 0.f, 0.f, 0.f, 0.f, 0.f, 0.f};
    #pragma unroll
    for (int k = 0; k < 8; ++k) {
        float wxv = __expf(m8[k] - M);
        S += s8[k] * wxv;
        uint4 hv = *(const uint4*)(pb + k * 4608 + 16 + cq * 16);
        u32 uu[4] = {hv.x, hv.y, hv.z, hv.w};
        #pragma unroll
        for (int i = 0; i < 4; ++i) {
            accv[2 * i]     += wxv * __uint_as_float((uu[i] & 0xffffu) << 16);
            accv[2 * i + 1] += wxv * __uint_as_float(uu[i] & 0xffff0000u);
        }
    }
    float inv = (S > 0.f) ? 1.f / S : 0.f;
    float* ob = out + (size_t)b * 786432 + 524288 + l;
    #pragma unroll
    for (int i = 0; i < 8; ++i) ob[(size_t)(cq * 8 + i) * 4096] = accv[i] * inv;
}

extern "C" void kernel_launch(void* const* d_in, const int* in_sizes, int n_in,
                              void* d_out, int out_size, void* d_ws, size_t ws_size,
                              hipStream_t stream)
{
    const float* x    = (const float*)d_in[0];
    const float* mask = (const float*)d_in[1];
    float* out = (float*)d_out;
    char* ws = (char*)d_ws;

    u16* latb = (u16*)(ws + OFF_LATB);
    u16* knb  = (u16*)(ws + OFF_KNB);
    u16* forb = (u16*)(ws + OFF_FORB);
    u32* fbits = (u32*)(ws + OFF_FBITS);
    int* rows  = (int*)(ws + OFF_ROWS);
    int* cnt   = (int*)(ws + OFF_CNT);
    char* part = ws + OFF_PART;

    k_prep<<<1537, 256, 0, stream>>>((const float4*)x, (float4*)out, fbits, cnt);
    k_compact<<<16, 256, 0, stream>>>(mask, rows, cnt, fbits);
    k_norm<<<32, 256, 0, stream>>>(x, latb, knb, forb);
    k_flash<<<dim3(128, 8, 2), 256, 0, stream>>>(latb, knb, forb, fbits, rows, cnt, part);
    k_reduce<<<dim3(128, 2), 256, 0, stream>>>(rows, cnt, part, out);
}

// Round 4
// 143.747 us; speedup vs baseline: 5.4440x; 1.1553x over previous
//
#include <hip/hip_runtime.h>
#include <math.h>

// InnerPatchSoftShiftTriple — v4: MFMA 32x32x16, U-in-registers, tripled pre-swizzled
// G array (garr) staged via global_load_lds, 2 barriers per k-tile.
//
// s[l,k] = sum_{bb,aa,c} lat[c][R(l,bb,aa)] * knorm[c][R(k,bb,aa)]
// R(m,bb,aa) = Tinv(T(m)+bb-1) + (aa-1), valid iff intermediate/final in [0,L)
// T(m)=Tinv(m)=((m&63)<<6)|(m>>6).  k swept as k=Tinv(k'), k' contiguous.
// garr[b][s_g=m'+1][aa][c] = knorm[Tinv(m')+aa-1][c] (0 if invalid), stored with
// byte offset (aa*128+c8*16) ^ ((s_g&7)<<4) per slot -> LDS slab reads are 2-way-bank.

#define L 4096

typedef unsigned int   u32;
typedef unsigned short u16;
typedef short  short8 __attribute__((ext_vector_type(8)));
typedef float  f32x16 __attribute__((ext_vector_type(16)));

#define MFMA32(a, b, c) __builtin_amdgcn_mfma_f32_32x32x16_bf16((a), (b), (c), 0, 0, 0)

__device__ __forceinline__ u16 f2bf(float f) {
    u32 u = __float_as_uint(f);
    u32 r = (u + 0x7FFFu + ((u >> 16) & 1u)) >> 16;
    return (u16)r;
}

__device__ __forceinline__ void lds_async16(void* lds, const void* g) {
    __builtin_amdgcn_global_load_lds((const __attribute__((address_space(1))) u32*)g,
                                     (__attribute__((address_space(3))) u32*)lds, 16, 0, 0);
}

// ---- ws layout (bytes) ----
#define OFF_LATB  0u          // u16[2][4096][64] raw latter (transposed)
#define OFF_FORB  1048576u    // u16[2][4096][64] former (transposed)
#define OFF_GARR  2097152u    // 2 x 4104 slots x 384 B tripled swizzled knorm
#define GARR_BB   1575936u    // bytes per batch (4104*384)
#define OFF_FBITS 5249024u    // u32[128] flag bitmap (transposed order)
#define OFF_ROWS  5249536u    // int[4096]
#define OFF_CNT   5265920u    // int
#define OFF_PART  5266432u    // [2][128][8] x (32 rows x 144B: m f32, s f32, pad, 64 bf16)
#define OFF_KNB   5266432u    // u16[2][4096][64] normalized latter (ALIASES part; dead before k_flash)
// end = 5266432 + 9437184 = 14,703,616 B

// ---------------- pre1: passthrough copy + zero shift | norm/pack | compact ----------------
__global__ void k_pre1(const float4* __restrict__ x4, float4* __restrict__ out4,
                       const float* __restrict__ x, const float* __restrict__ mask,
                       u16* __restrict__ latb, u16* __restrict__ knb, u16* __restrict__ forb,
                       int* __restrict__ rows, int* __restrict__ cnt, u32* __restrict__ fbits)
{
    const int blk = blockIdx.x, t = threadIdx.x;
    if (blk < 1537) {
        int i = blk * 256 + t;
        if (i < 262144) {
            int b = i >> 17, j = i & 131071;
            out4[b * 196608 + j] = x4[b * 131072 + j];
        } else if (i < 393216) {
            int z = i - 262144; int b = z >> 16, j = z & 65535;
            out4[b * 196608 + 131072 + j] = make_float4(0.f, 0.f, 0.f, 0.f);
        }
    } else if (blk < 1569) {
        int tid = (blk - 1537) * 256 + t;   // 8192
        int b = tid >> 12, l = tid & 4095;
        const float* xb = x + (size_t)b * 524288;
        float v[64]; float ss = 0.f;
        #pragma unroll
        for (int c = 0; c < 64; ++c) { v[c] = xb[(64 + c) * 4096 + l]; ss += v[c] * v[c]; }
        float inv = 1.f / fmaxf(sqrtf(ss), 1e-4f);
        u16* lr = latb + (size_t)(b * 4096 + l) * 64;
        u16* kr = knb  + (size_t)(b * 4096 + l) * 64;
        #pragma unroll
        for (int c8 = 0; c8 < 8; ++c8) {
            u32 wl[4], wk[4];
            #pragma unroll
            for (int i = 0; i < 4; ++i) {
                float a = v[c8 * 8 + 2 * i], bb2 = v[c8 * 8 + 2 * i + 1];
                wl[i] = (u32)f2bf(a) | ((u32)f2bf(bb2) << 16);
                wk[i] = (u32)f2bf(a * inv) | ((u32)f2bf(bb2 * inv) << 16);
            }
            uint4 pl = make_uint4(wl[0], wl[1], wl[2], wl[3]);
            uint4 pk = make_uint4(wk[0], wk[1], wk[2], wk[3]);
            *(uint4*)(lr + c8 * 8) = pl;
            *(uint4*)(kr + c8 * 8) = pk;
        }
        u16* fr = forb + (size_t)(b * 4096 + l) * 64;
        #pragma unroll
        for (int c8 = 0; c8 < 8; ++c8) {
            u32 wf[4];
            #pragma unroll
            for (int i = 0; i < 4; ++i) {
                float a = xb[(c8 * 8 + 2 * i) * 4096 + l];
                float bb2 = xb[(c8 * 8 + 2 * i + 1) * 4096 + l];
                wf[i] = (u32)f2bf(a) | ((u32)f2bf(bb2) << 16);
            }
            uint4 pf = make_uint4(wf[0], wf[1], wf[2], wf[3]);
            *(uint4*)(fr + c8 * 8) = pf;
        }
    } else {
        // single-block compaction (no cross-block races)
        __shared__ int lcnt;
        __shared__ u32 lb[128];
        if (t == 0) lcnt = 0;
        if (t < 128) lb[t] = 0u;
        __syncthreads();
        for (int i = t; i < L; i += 256) {
            if (mask[i] > 0.5f) {
                int p = atomicAdd(&lcnt, 1); rows[p] = i;
                int kp = ((i & 63) << 6) | (i >> 6);
                atomicOr(&lb[kp >> 5], 1u << (kp & 31));
            }
        }
        __syncthreads();
        if (t < 128) fbits[t] = lb[t];
        if (t == 0) cnt[0] = lcnt;
    }
}

// ---------------- pre2: build tripled pre-swizzled garr from knb ----------------
__global__ void k_garr(const u16* __restrict__ knb, char* __restrict__ garr)
{
    int tid = blockIdx.x * 256 + threadIdx.x;
    if (tid >= 2 * 4104 * 3) return;
    int b = tid / 12312; int rem = tid - b * 12312;
    int sg = rem / 3, aa = rem - 3 * (rem / 3);
    int mp = sg - 1;
    char* dst = garr + (size_t)b * GARR_BB + (size_t)sg * 384;
    int key = (sg & 7) << 4;
    const u16* src = nullptr;
    if (mp >= 0 && mp < L) {
        int q = (((mp & 63) << 6) | (mp >> 6)) + aa - 1;
        if (q >= 0 && q < L) src = knb + (size_t)b * 262144 + (size_t)q * 64;
    }
    #pragma unroll
    for (int c8 = 0; c8 < 8; ++c8) {
        uint4 v = src ? *(const uint4*)(src + c8 * 8) : make_uint4(0, 0, 0, 0);
        *(uint4*)(dst + ((aa * 128 + c8 * 16) ^ key)) = v;
    }
}

// ---------------- main flash kernel ----------------
// LDS (80000 B, 2 blocks/CU):
//  slab  0..52224      : 136 slots x 384 B (tripled G, XOR-swizzled)   | aliased by um f32[4][32][66]
//  F_s   52224..69632  : u16[64][136]  former^T tile [ch][col]
//  p_s   69632..79872  : u16[4][32][40] per-wave P fragments
//  rl_s  79872..80000  : int[32]
__global__ __launch_bounds__(256, 2)
void k_flash(const u16* __restrict__ latb, const u16* __restrict__ forb,
             const char* __restrict__ garr, const u32* __restrict__ fbits,
             const int* __restrict__ rows, const int* __restrict__ cnt,
             char* __restrict__ part)
{
    __shared__ __align__(16) char smem[80000];
    char* slab = smem;
    u16*  F_s  = (u16*)(smem + 52224);
    u16*  p_s  = (u16*)(smem + 69632);
    int*  rl_s = (int*)(smem + 79872);

    const int t = threadIdx.x;
    const int rt = blockIdx.x, ks = blockIdx.y, b = blockIdx.z;
    const int count = cnt[0];
    const int base = rt * 32;
    if (base >= count) return;
    const int nact = min(32, count - base);
    if (t < 32) rl_s[t] = rows[base + min(t, nact - 1)];
    __syncthreads();

    const int l = t & 63, w = t >> 6;
    const int li = l & 31, hi = l >> 5;
    const size_t boff = (size_t)b * 262144;   // u16 elems per batch

    // ---- U gather into registers (B-frags: n=li row, k=(hi)*8+j per 16-chunk) ----
    const u16* zp = (const u16*)garr;   // slot 0 of garr = 384B of zeros
    int gl = rl_s[li];
    int tl0 = ((gl & 63) << 6) | (gl >> 6);
    const u16* rp[9];
    #pragma unroll
    for (int tap = 0; tap < 9; ++tap) {
        int bb = tap / 3, aa = tap - 3 * (tap / 3);
        int mp = tl0 + bb - 1;
        const u16* p = zp;
        if (mp >= 0 && mp < L) {
            int q = (((mp & 63) << 6) | (mp >> 6)) + aa - 1;
            if (q >= 0 && q < L) p = latb + boff + (size_t)q * 64;
        }
        rp[tap] = p;
    }
    short8 bu[36];
    #pragma unroll
    for (int q = 0; q < 36; ++q) {
        int tap = q >> 2, Ksi = q & 3;
        bu[q] = *(const short8*)(rp[tap] + Ksi * 16 + hi * 8);
    }

    float mrun = -INFINITY, srun = 0.f;
    f32x16 acc0, acc1;
    #pragma unroll
    for (int r = 0; r < 16; ++r) { acc0[r] = 0.f; acc1[r] = 0.f; }

    const int kp0 = ks * 512;
    const char* gb = garr + (size_t)b * GARR_BB;

    for (int kt = 0; kt < 4; ++kt) {
        const int k0p = kp0 + kt * 128;
        __syncthreads();   // slab & F_s free (prev consumers done)

        // stage slab: 51 KB linear global_load_lds from pre-swizzled garr
        const char* gw = gb + (size_t)k0p * 384;
        #pragma unroll
        for (int i = 0; i < 13; ++i) {
            int idx = w + 4 * i;
            if (idx < 51)
                lds_async16(slab + idx * 1024, gw + idx * 1024 + l * 16);
        }

        // stage F_s[ch][col] (transposed former tile), reg round-trip
        {
            int kpA = k0p + 2 * l, kpB = kpA + 1;
            int kA = ((kpA & 63) << 6) | (kpA >> 6);
            int kB = ((kpB & 63) << 6) | (kpB >> 6);
            const u32* pa = (const u32*)(forb + boff + (size_t)kA * 64 + w * 16);
            const u32* pc = (const u32*)(forb + boff + (size_t)kB * 64 + w * 16);
            uint4 A0 = *(const uint4*)pa, A1 = *(const uint4*)(pa + 4);
            uint4 B0 = *(const uint4*)pc, B1 = *(const uint4*)(pc + 4);
            u32 av[8] = {A0.x, A0.y, A0.z, A0.w, A1.x, A1.y, A1.z, A1.w};
            u32 bv[8] = {B0.x, B0.y, B0.z, B0.w, B1.x, B1.y, B1.z, B1.w};
            #pragma unroll
            for (int i2 = 0; i2 < 8; ++i2) {
                u32 w0 = (av[i2] & 0xffffu) | (bv[i2] << 16);
                u32 w1 = (av[i2] >> 16) | (bv[i2] & 0xffff0000u);
                *(u32*)((char*)F_s + (w * 16 + 2 * i2) * 272 + l * 4) = w0;
                *(u32*)((char*)F_s + (w * 16 + 2 * i2 + 1) * 272 + l * 4) = w1;
            }
        }
        asm volatile("s_waitcnt vmcnt(0)" ::: "memory");
        __syncthreads();

        // ---- score: S^T tile (M=32 k'cols, N=32 rows), K=576 ----
        f32x16 sc;
        #pragma unroll
        for (int r = 0; r < 16; ++r) sc[r] = 0.f;
        const int slot_base = w * 32 + li;
        #pragma unroll
        for (int tap = 0; tap < 9; ++tap) {
            int bb = tap / 3, aa = tap - 3 * (tap / 3);
            int sl = slot_base + bb;
            int key = (sl & 7) << 4;
            int base_b = sl * 384 + aa * 128 + hi * 16;
            #pragma unroll
            for (int Ksi = 0; Ksi < 4; ++Ksi) {
                short8 ag = *(const short8*)(slab + ((base_b + Ksi * 32) ^ key));
                sc = MFMA32(ag, bu[tap * 4 + Ksi], sc);
            }
        }

        // ---- mask + online softmax (lane-local row li; k' = k0p+w*32+kloc) ----
        u32 bits = fbits[(k0p >> 5) + w];
        float sv[16]; float mx = -INFINITY;
        #pragma unroll
        for (int r = 0; r < 16; ++r) {
            int kloc = (r & 3) + 8 * (r >> 2) + 4 * hi;
            float s = sc[r];
            if ((bits >> kloc) & 1) s = -INFINITY;
            sv[r] = s; mx = fmaxf(mx, s);
        }
        mx = fmaxf(mx, __shfl_xor(mx, 32, 64));
        float newm = fmaxf(mrun, mx);
        float fac, tsum = 0.f;
        u16 pb[16];
        if (newm > -INFINITY) {
            fac = __expf(mrun - newm);
            #pragma unroll
            for (int r = 0; r < 16; ++r) { float p = __expf(sv[r] - newm); tsum += p; pb[r] = f2bf(p); }
        } else {
            fac = 1.f;
            #pragma unroll
            for (int r = 0; r < 16; ++r) pb[r] = 0;
        }
        tsum += __shfl_xor(tsum, 32, 64);
        srun = srun * fac + tsum;
        mrun = newm;
        #pragma unroll
        for (int rq = 0; rq < 8; ++rq) {
            int r = rq * 2;
            int kloc = (r & 3) + 8 * (r >> 2) + 4 * hi;
            u32 pw = (u32)pb[r] | ((u32)pb[r + 1] << 16);
            *(u32*)(p_s + w * 1280 + li * 40 + kloc) = pw;
        }

        // ---- rescale acc (fac per row via bpermute), then PV ----
        #pragma unroll
        for (int r = 0; r < 16; ++r) {
            int row = (r & 3) + 8 * (r >> 2) + 4 * hi;
            float fr = __shfl(fac, row, 64);
            acc0[r] *= fr; acc1[r] *= fr;
        }
        #pragma unroll
        for (int Ksi2 = 0; Ksi2 < 2; ++Ksi2) {
            short8 pa2 = *(const short8*)(p_s + w * 1280 + li * 40 + Ksi2 * 16 + hi * 8);
            short8 f0 = *(const short8*)(F_s + li * 136 + w * 32 + Ksi2 * 16 + hi * 8);
            short8 f1 = *(const short8*)(F_s + (32 + li) * 136 + w * 32 + Ksi2 * 16 + hi * 8);
            acc0 = MFMA32(pa2, f0, acc0);
            acc1 = MFMA32(pa2, f1, acc1);
        }
    }

    // ---- merge 4 waves (um aliases slab), write bf16 partials ----
    __syncthreads();
    float* um = (float*)smem;   // [4][32][66]
    if (l < 32) { um[(w * 32 + li) * 66] = mrun; um[(w * 32 + li) * 66 + 1] = srun; }
    #pragma unroll
    for (int r = 0; r < 16; ++r) {
        int row = (r & 3) + 8 * (r >> 2) + 4 * hi;
        um[(w * 32 + row) * 66 + 2 + li] = acc0[r];
        um[(w * 32 + row) * 66 + 2 + 32 + li] = acc1[r];
    }
    __syncthreads();
    {
        int row = t >> 3, cq = t & 7;
        float m4[4], s4[4];
        #pragma unroll
        for (int wv = 0; wv < 4; ++wv) {
            m4[wv] = um[(wv * 32 + row) * 66];
            s4[wv] = um[(wv * 32 + row) * 66 + 1];
        }
        float M = fmaxf(fmaxf(m4[0], m4[1]), fmaxf(m4[2], m4[3]));
        float S = 0.f; float wx[4];
        if (M > -INFINITY) {
            #pragma unroll
            for (int wv = 0; wv < 4; ++wv) { wx[wv] = __expf(m4[wv] - M); S += s4[wv] * wx[wv]; }
        } else {
            wx[0] = wx[1] = wx[2] = wx[3] = 0.f;
        }
        char* pp = part + ((size_t)((b * 128 + rt) * 8 + ks)) * 4608 + row * 144;
        u16 h[8];
        #pragma unroll
        for (int i = 0; i < 8; ++i) {
            int ch = cq * 8 + i;
            float v = 0.f;
            #pragma unroll
            for (int wv = 0; wv < 4; ++wv) v += wx[wv] * um[(wv * 32 + row) * 66 + 2 + ch];
            h[i] = f2bf(v);
        }
        if (cq == 0) { *(float*)pp = M; *(float*)(pp + 4) = S; }
        uint4 hw;
        hw.x = (u32)h[0] | ((u32)h[1] << 16); hw.y = (u32)h[2] | ((u32)h[3] << 16);
        hw.z = (u32)h[4] | ((u32)h[5] << 16); hw.w = (u32)h[6] | ((u32)h[7] << 16);
        *(uint4*)(pp + 16 + cq * 16) = hw;
    }
}

// ---------------- combine k-split partials, write shift ----------------
__global__ void k_reduce(const int* __restrict__ rows, const int* __restrict__ cnt,
                         const char* __restrict__ part, float* __restrict__ out)
{
    int t = threadIdx.x;
    int row = t >> 3, cq = t & 7;
    int rt = blockIdx.x, b = blockIdx.y;
    int count = cnt[0];
    int slot = rt * 32 + row;
    if (slot >= count) return;
    int l = rows[slot];
    const char* pb = part + ((size_t)((b * 128 + rt) * 8)) * 4608 + row * 144;
    float M = -INFINITY, m8[8], s8[8];
    #pragma unroll
    for (int k = 0; k < 8; ++k) {
        m8[k] = *(const float*)(pb + k * 4608);
        s8[k] = *(const float*)(pb + k * 4608 + 4);
        M = fmaxf(M, m8[k]);
    }
    if (!(M > -INFINITY)) return;
    float S = 0.f; float accv[8] = {0.f, 0.f, 0.f, 0.f, 0.f, 0.f, 0.f, 0.f};
    #pragma unroll
    for (int k = 0; k < 8; ++k) {
        float wxv = __expf(m8[k] - M);
        S += s8[k] * wxv;
        uint4 hv = *(const uint4*)(pb + k * 4608 + 16 + cq * 16);
        u32 uu[4] = {hv.x, hv.y, hv.z, hv.w};
        #pragma unroll
        for (int i = 0; i < 4; ++i) {
            accv[2 * i]     += wxv * __uint_as_float((uu[i] & 0xffffu) << 16);
            accv[2 * i + 1] += wxv * __uint_as_float(uu[i] & 0xffff0000u);
        }
    }
    float inv = (S > 0.f) ? 1.f / S : 0.f;
    float* ob = out + (size_t)b * 786432 + 524288 + l;
    #pragma unroll
    for (int i = 0; i < 8; ++i) ob[(size_t)(cq * 8 + i) * 4096] = accv[i] * inv;
}

extern "C" void kernel_launch(void* const* d_in, const int* in_sizes, int n_in,
                              void* d_out, int out_size, void* d_ws, size_t ws_size,
                              hipStream_t stream)
{
    const float* x    = (const float*)d_in[0];
    const float* mask = (const float*)d_in[1];
    float* out = (float*)d_out;
    char* ws = (char*)d_ws;

    u16* latb = (u16*)(ws + OFF_LATB);
    u16* forb = (u16*)(ws + OFF_FORB);
    char* garr = ws + OFF_GARR;
    u32* fbits = (u32*)(ws + OFF_FBITS);
    int* rows  = (int*)(ws + OFF_ROWS);
    int* cnt   = (int*)(ws + OFF_CNT);
    char* part = ws + OFF_PART;
    u16* knb   = (u16*)(ws + OFF_KNB);   // aliases part (dead before k_flash writes part)

    k_pre1<<<1570, 256, 0, stream>>>((const float4*)x, (float4*)out, x, mask,
                                     latb, knb, forb, rows, cnt, fbits);
    k_garr<<<97, 256, 0, stream>>>(knb, garr);
    k_flash<<<dim3(128, 8, 2), 256, 0, stream>>>(latb, forb, garr, fbits, rows, cnt, part);
    k_reduce<<<dim3(128, 2), 256, 0, stream>>>(rows, cnt, part, out);
}